// Round 1
// baseline (1779.015 us; speedup 1.0000x reference)
//
#include <hip/hip_runtime.h>
#include <math.h>

#define N   111
#define NP  112
#define NE  4000
#define KP  100
#define CA  56
#define NT  512

__device__ __constant__ int d_LEFT[55] = {6,5,55,1,98,71,73,77,63,96,79,15,104,4,25,23,41,43,45,17,61,65,59,57,86,21,35,37,39,94,110,3,69,81,84,100,102,106,47,27,75,2,67,19,49,31,33,108,51,53,88,90,92,29,0};
__device__ __constant__ int d_RIGHT[55] = {13,12,54,8,97,70,72,76,62,95,78,14,103,11,24,22,40,42,44,16,60,64,58,56,85,20,34,36,38,93,109,10,68,80,83,99,101,105,46,26,74,9,66,18,48,30,32,107,50,52,87,89,91,28,7};

__global__ __launch_bounds__(NT, 1)
void brain_fused(const float* __restrict__ features,
                 const float* __restrict__ edge_attr,
                 const int*   __restrict__ edge_index,
                 const float* __restrict__ Wl1, const float* __restrict__ bl1,
                 const float* __restrict__ Wr1, const float* __restrict__ br1,
                 const float* __restrict__ Wl2, const float* __restrict__ bl2,
                 const float* __restrict__ Wr2, const float* __restrict__ br2,
                 const float* __restrict__ Wg1, const float* __restrict__ bg1,
                 const float* __restrict__ Wrel, const float* __restrict__ brel,
                 const float* __restrict__ Wroot,
                 const float* __restrict__ Wc0, const float* __restrict__ Wc1,
                 const float* __restrict__ Wc2, const float* __restrict__ bc,
                 float* __restrict__ out)
{
    // ---- LDS (total ~160.6 KB, fits 163840) ----
    __shared__ float Ag[N*NP];      // weighted adjacency A[t,s]; later rebuilt as A_p
    __shared__ float T64[NP*64];    // staging dm.(x@W) (pad row 111 = 0); later ass[111*56]
    __shared__ float H1[N*64];      // h1; later s2[111*56]
    __shared__ float T20[NP*20];    // 20-col staging (pad row)
    __shared__ float H2g[NP*20];    // post-global h2 (pad row)
    __shared__ float H2[N*20];
    __shared__ float Tx1[N*20];
    __shared__ float Tx2[N*20];
    __shared__ float disL[N], disR[N], disG[N], disC[N];
    __shared__ float dmL[N], dmR[N];
    __shared__ float scoreS[N];
    __shared__ int   mapS[N];
    __shared__ int   hemiS[N];
    __shared__ int   permS[KP];
    __shared__ int   spS[KP];
    __shared__ float HcS[CA*20];

    const int b    = blockIdx.x;
    const int tid  = threadIdx.x;
    const int lane = tid & 63;
    const int wv   = tid >> 6;
    const float* x = features + (size_t)b * (N*N);
    float* assS = T64;   // aliases
    float* s2S  = H1;

    // ---- P0 init ----
    for (int o = tid; o < N*NP;  o += NT) Ag[o]  = 0.f;
    for (int o = tid; o < N*64;  o += NT) H1[o]  = 0.f;
    for (int o = tid; o < N*20;  o += NT) H2[o]  = 0.f;
    for (int o = tid; o < NP*20; o += NT) H2g[o] = 0.f;
    for (int o = tid; o < N;     o += NT) hemiS[o] = 2;
    __syncthreads();
    if (tid < 55) hemiS[d_LEFT[tid]] = 0;
    else if (tid < 110) hemiS[d_RIGHT[tid-55]] = 1;
    __syncthreads();

    // ---- P1 scatter edges: A[dst,src] += w ----
    for (int e = tid; e < NE; e += NT) {
        int s = edge_index[e];
        int t = edge_index[NE + e];
        atomicAdd(&Ag[t*NP + s], edge_attr[(size_t)b*NE + e]);
    }
    __syncthreads();

    // ---- P2 degrees (row sums of A+I per mask) ----
    for (int i = tid; i < N; i += NT) {
        float sl = 0.f, sr = 0.f, sg = 0.f;
        for (int j = 0; j < N; ++j) {
            float a = Ag[i*NP+j];
            int hj = hemiS[j];
            sg += a;
            sl += (hj == 0) ? a : 0.f;
            sr += (hj == 1) ? a : 0.f;
        }
        int hi = hemiS[i];
        float dL = (hi == 0) ? sl + 1.f : 1.f;
        float dR = (hi == 1) ? sr + 1.f : 1.f;
        float dG = sg + 1.f;
        float rl = 1.f / sqrtf(dL);
        float rr = 1.f / sqrtf(dR);
        float rg = 1.f / sqrtf(dG);
        disL[i] = rl; disR[i] = rr; disG[i] = rg;
        dmL[i] = (hi == 0) ? rl : 0.f;
        dmR[i] = (hi == 1) ? rr : 0.f;
    }
    __syncthreads();

    // ================= layer 1, LEFT =================
    // P3: T64[j,c] = dmL[j] * (x @ Wl1)[j,c], LEFT rows only
    for (int o = tid; o < NP*64; o += NT) T64[o] = 0.f;
    __syncthreads();
    for (int k = wv; k < 55; k += 8) {
        int i = d_LEFT[k];
        const float* xr = x + i*N;
        float acc = 0.f;
        #pragma unroll 4
        for (int j = 0; j < N; ++j) acc += xr[j] * Wl1[j*64 + lane];
        T64[i*64 + lane] = dmL[i] * acc;
    }
    __syncthreads();
    // P4: H1[LEFT] = lrelu(disL[i]*(sum_j Ag[i,j]*T'[j,c] + T'[i,c]) + bl1)
    {
        int iu[7];
        #pragma unroll
        for (int u = 0; u < 7; ++u) { int k = wv + 8*u; iu[u] = d_LEFT[(k < 55) ? k : 54]; }
        float acc[7] = {0,0,0,0,0,0,0};
        for (int j4 = 0; j4 < 28; ++j4) {
            float t0 = T64[(4*j4+0)*64 + lane];
            float t1 = T64[(4*j4+1)*64 + lane];
            float t2 = T64[(4*j4+2)*64 + lane];
            float t3 = T64[(4*j4+3)*64 + lane];
            #pragma unroll
            for (int u = 0; u < 7; ++u) {
                const float4 a4 = *(const float4*)&Ag[iu[u]*NP + 4*j4];
                acc[u] += a4.x*t0 + a4.y*t1 + a4.z*t2 + a4.w*t3;
            }
        }
        float bv = bl1[lane];
        #pragma unroll
        for (int u = 0; u < 7; ++u) {
            int k = wv + 8*u;
            if (k < 55) {
                int i = iu[u];
                float h = disL[i] * (acc[u] + T64[i*64+lane]) + bv;
                H1[i*64+lane] = (h > 0.f) ? h : 0.01f*h;
            }
        }
    }
    __syncthreads();

    // ================= layer 1, RIGHT =================
    for (int o = tid; o < NP*64; o += NT) T64[o] = 0.f;
    __syncthreads();
    for (int k = wv; k < 55; k += 8) {
        int i = d_RIGHT[k];
        const float* xr = x + i*N;
        float acc = 0.f;
        #pragma unroll 4
        for (int j = 0; j < N; ++j) acc += xr[j] * Wr1[j*64 + lane];
        T64[i*64 + lane] = dmR[i] * acc;
    }
    __syncthreads();
    {
        int iu[7];
        #pragma unroll
        for (int u = 0; u < 7; ++u) { int k = wv + 8*u; iu[u] = d_RIGHT[(k < 55) ? k : 54]; }
        float acc[7] = {0,0,0,0,0,0,0};
        for (int j4 = 0; j4 < 28; ++j4) {
            float t0 = T64[(4*j4+0)*64 + lane];
            float t1 = T64[(4*j4+1)*64 + lane];
            float t2 = T64[(4*j4+2)*64 + lane];
            float t3 = T64[(4*j4+3)*64 + lane];
            #pragma unroll
            for (int u = 0; u < 7; ++u) {
                const float4 a4 = *(const float4*)&Ag[iu[u]*NP + 4*j4];
                acc[u] += a4.x*t0 + a4.y*t1 + a4.z*t2 + a4.w*t3;
            }
        }
        float bv = br1[lane];
        #pragma unroll
        for (int u = 0; u < 7; ++u) {
            int k = wv + 8*u;
            if (k < 55) {
                int i = iu[u];
                float h = disR[i] * (acc[u] + T64[i*64+lane]) + bv;
                H1[i*64+lane] = (h > 0.f) ? h : 0.01f*h;
            }
        }
    }
    __syncthreads();

    // ================= layer 2, LEFT =================
    // P7: T20 = dmL . (H1 @ Wl2), LEFT rows
    for (int o = tid; o < NP*20; o += NT) T20[o] = 0.f;
    __syncthreads();
    for (int o = tid; o < 55*20; o += NT) {
        int ki = o / 20, c = o % 20;
        int i = d_LEFT[ki];
        float acc = 0.f;
        #pragma unroll
        for (int k = 0; k < 64; ++k) acc += H1[i*64+k] * Wl2[k*20+c];
        T20[i*20+c] = dmL[i] * acc;
    }
    __syncthreads();
    // P8: H2[LEFT]
    for (int o = tid; o < 220; o += NT) {
        int ki0 = o / 20, c = o % 20;
        int rows[5];
        #pragma unroll
        for (int u = 0; u < 5; ++u) rows[u] = d_LEFT[ki0 + 11*u];
        float acc[5] = {0,0,0,0,0};
        for (int j4 = 0; j4 < 28; ++j4) {
            float t0 = T20[(4*j4+0)*20 + c];
            float t1 = T20[(4*j4+1)*20 + c];
            float t2 = T20[(4*j4+2)*20 + c];
            float t3 = T20[(4*j4+3)*20 + c];
            #pragma unroll
            for (int u = 0; u < 5; ++u) {
                const float4 a4 = *(const float4*)&Ag[rows[u]*NP + 4*j4];
                acc[u] += a4.x*t0 + a4.y*t1 + a4.z*t2 + a4.w*t3;
            }
        }
        #pragma unroll
        for (int u = 0; u < 5; ++u) {
            int i = rows[u];
            float h = disL[i] * (acc[u] + T20[i*20+c]) + bl2[c];
            H2[i*20+c] = (h > 0.f) ? h : 0.01f*h;
        }
    }
    __syncthreads();

    // ================= layer 2, RIGHT =================
    for (int o = tid; o < NP*20; o += NT) T20[o] = 0.f;
    __syncthreads();
    for (int o = tid; o < 55*20; o += NT) {
        int ki = o / 20, c = o % 20;
        int i = d_RIGHT[ki];
        float acc = 0.f;
        #pragma unroll
        for (int k = 0; k < 64; ++k) acc += H1[i*64+k] * Wr2[k*20+c];
        T20[i*20+c] = dmR[i] * acc;
    }
    __syncthreads();
    for (int o = tid; o < 220; o += NT) {
        int ki0 = o / 20, c = o % 20;
        int rows[5];
        #pragma unroll
        for (int u = 0; u < 5; ++u) rows[u] = d_RIGHT[ki0 + 11*u];
        float acc[5] = {0,0,0,0,0};
        for (int j4 = 0; j4 < 28; ++j4) {
            float t0 = T20[(4*j4+0)*20 + c];
            float t1 = T20[(4*j4+1)*20 + c];
            float t2 = T20[(4*j4+2)*20 + c];
            float t3 = T20[(4*j4+3)*20 + c];
            #pragma unroll
            for (int u = 0; u < 5; ++u) {
                const float4 a4 = *(const float4*)&Ag[rows[u]*NP + 4*j4];
                acc[u] += a4.x*t0 + a4.y*t1 + a4.z*t2 + a4.w*t3;
            }
        }
        #pragma unroll
        for (int u = 0; u < 5; ++u) {
            int i = rows[u];
            float h = disR[i] * (acc[u] + T20[i*20+c]) + br2[c];
            H2[i*20+c] = (h > 0.f) ? h : 0.01f*h;
        }
    }
    __syncthreads();

    // ================= global GCN =================
    // P11: T20 = disG . (H2 @ Wg1)
    for (int o = tid; o < N*20; o += NT) {
        int i = o/20, c = o%20;
        float acc = 0.f;
        #pragma unroll
        for (int k = 0; k < 20; ++k) acc += H2[i*20+k] * Wg1[k*20+c];
        T20[o] = disG[i] * acc;
    }
    __syncthreads();
    // P12: H2g = lrelu(disG[i]*(Ag@T20 + T20[i]) + bg1)
    for (int o = tid; o < 320; o += NT) {
        int i0 = o/20, c = o%20;
        int rows[7];
        #pragma unroll
        for (int u = 0; u < 7; ++u) { int i = i0 + 16*u; rows[u] = (i < N) ? i : (N-1); }
        float acc[7] = {0,0,0,0,0,0,0};
        for (int j4 = 0; j4 < 28; ++j4) {
            float t0 = T20[(4*j4+0)*20 + c];
            float t1 = T20[(4*j4+1)*20 + c];
            float t2 = T20[(4*j4+2)*20 + c];
            float t3 = T20[(4*j4+3)*20 + c];
            #pragma unroll
            for (int u = 0; u < 7; ++u) {
                const float4 a4 = *(const float4*)&Ag[rows[u]*NP + 4*j4];
                acc[u] += a4.x*t0 + a4.y*t1 + a4.z*t2 + a4.w*t3;
            }
        }
        #pragma unroll
        for (int u = 0; u < 7; ++u) {
            int i = i0 + 16*u;
            if (i < N) {
                float h = disG[i] * (acc[u] + T20[i*20+c]) + bg1[c];
                H2g[i*20+c] = (h > 0.f) ? h : 0.01f*h;
            }
        }
    }
    __syncthreads();

    // ================= SAG score =================
    // P13: G = Ag @ H2g -> T20
    for (int o = tid; o < 320; o += NT) {
        int i0 = o/20, c = o%20;
        int rows[7];
        #pragma unroll
        for (int u = 0; u < 7; ++u) { int i = i0 + 16*u; rows[u] = (i < N) ? i : (N-1); }
        float acc[7] = {0,0,0,0,0,0,0};
        for (int j4 = 0; j4 < 28; ++j4) {
            float t0 = H2g[(4*j4+0)*20 + c];
            float t1 = H2g[(4*j4+1)*20 + c];
            float t2 = H2g[(4*j4+2)*20 + c];
            float t3 = H2g[(4*j4+3)*20 + c];
            #pragma unroll
            for (int u = 0; u < 7; ++u) {
                const float4 a4 = *(const float4*)&Ag[rows[u]*NP + 4*j4];
                acc[u] += a4.x*t0 + a4.y*t1 + a4.z*t2 + a4.w*t3;
            }
        }
        #pragma unroll
        for (int u = 0; u < 7; ++u) {
            int i = i0 + 16*u;
            if (i < N) T20[i*20+c] = acc[u];
        }
    }
    __syncthreads();
    // P14: score = tanh(G @ Wrel + brel + H2g @ Wroot)
    if (tid < N) {
        float u_ = brel[0];
        #pragma unroll
        for (int c = 0; c < 20; ++c) u_ += T20[tid*20+c]*Wrel[c] + H2g[tid*20+c]*Wroot[c];
        scoreS[tid] = tanhf(u_);
    }
    __syncthreads();
    // P15: stable descending rank (matches argsort(-score) with index tie-break)
    if (tid < N) {
        float si = scoreS[tid];
        int r = 0;
        for (int j = 0; j < N; ++j) {
            float sj = scoreS[j];
            r += (sj > si || (sj == si && j < tid)) ? 1 : 0;
        }
        mapS[tid] = (r < KP) ? r : -1;
        if (r < KP) permS[r] = tid;
    }
    __syncthreads();
    // P16: sp = sorted(perm)
    if (tid < N && mapS[tid] >= 0) {
        int pos = 0;
        for (int j = 0; j < tid; ++j) pos += (mapS[j] >= 0) ? 1 : 0;
        spS[pos] = tid;
    }
    __syncthreads();

    // ================= filter_adj -> A_p (reuse Ag) =================
    for (int o = tid; o < N*NP; o += NT) Ag[o] = 0.f;
    __syncthreads();
    for (int e = tid; e < NE; e += NT) {
        int s = edge_index[e], t = edge_index[NE+e];
        int ms = mapS[s], mt = mapS[t];
        if (ms >= 0 && mt >= 0 && ms != mt) atomicAdd(&Ag[mt*NP+ms], 1.f);
    }
    __syncthreads();
    // P18: disC from column sums
    if (tid < N) {
        float d = 0.f;
        for (int i = 0; i < KP; ++i) d += Ag[i*NP + tid];
        disC[tid] = (d > 0.f) ? 1.f/sqrtf(d) : 0.f;
    }
    __syncthreads();

    // ================= Cheb Tx1 / Tx2 =================
    // P19a: T20 = disC . H2g
    for (int o = tid; o < N*20; o += NT) T20[o] = disC[o/20] * H2g[o];
    __syncthreads();
    // P19: Tx1 = -disC[i] * (Ap @ T20)
    for (int o = tid; o < 320; o += NT) {
        int i0 = o/20, c = o%20;
        int rows[7];
        #pragma unroll
        for (int u = 0; u < 7; ++u) { int i = i0 + 16*u; rows[u] = (i < N) ? i : (N-1); }
        float acc[7] = {0,0,0,0,0,0,0};
        for (int j4 = 0; j4 < 28; ++j4) {
            float t0 = T20[(4*j4+0)*20 + c];
            float t1 = T20[(4*j4+1)*20 + c];
            float t2 = T20[(4*j4+2)*20 + c];
            float t3 = T20[(4*j4+3)*20 + c];
            #pragma unroll
            for (int u = 0; u < 7; ++u) {
                const float4 a4 = *(const float4*)&Ag[rows[u]*NP + 4*j4];
                acc[u] += a4.x*t0 + a4.y*t1 + a4.z*t2 + a4.w*t3;
            }
        }
        #pragma unroll
        for (int u = 0; u < 7; ++u) {
            int i = i0 + 16*u;
            if (i < N) Tx1[i*20+c] = -disC[i]*acc[u];
        }
    }
    __syncthreads();
    // P20a: T20 = disC . Tx1
    for (int o = tid; o < N*20; o += NT) T20[o] = disC[o/20] * Tx1[o];
    __syncthreads();
    // P20: Tx2 = 2*(-disC[i]*(Ap@T20)) - H2g
    for (int o = tid; o < 320; o += NT) {
        int i0 = o/20, c = o%20;
        int rows[7];
        #pragma unroll
        for (int u = 0; u < 7; ++u) { int i = i0 + 16*u; rows[u] = (i < N) ? i : (N-1); }
        float acc[7] = {0,0,0,0,0,0,0};
        for (int j4 = 0; j4 < 28; ++j4) {
            float t0 = T20[(4*j4+0)*20 + c];
            float t1 = T20[(4*j4+1)*20 + c];
            float t2 = T20[(4*j4+2)*20 + c];
            float t3 = T20[(4*j4+3)*20 + c];
            #pragma unroll
            for (int u = 0; u < 7; ++u) {
                const float4 a4 = *(const float4*)&Ag[rows[u]*NP + 4*j4];
                acc[u] += a4.x*t0 + a4.y*t1 + a4.z*t2 + a4.w*t3;
            }
        }
        #pragma unroll
        for (int u = 0; u < 7; ++u) {
            int i = i0 + 16*u;
            if (i < N) Tx2[i*20+c] = -2.f*disC[i]*acc[u] - H2g[i*20+c];
        }
    }
    __syncthreads();

    // ================= assignment + diff-pool =================
    // P21: ass logits -> assS (aliases T64)
    for (int o = tid; o < N*CA; o += NT) {
        int i = o/CA, c = o%CA;
        float acc = bc[c];
        #pragma unroll
        for (int k = 0; k < 20; ++k) {
            acc += H2g[i*20+k]*Wc0[k*CA+c];
            acc += Tx1[i*20+k]*Wc1[k*CA+c];
            acc += Tx2[i*20+k]*Wc2[k*CA+c];
        }
        assS[o] = acc;
    }
    __syncthreads();
    // P21b: double softmax per row; s2 -> s2S (aliases H1)
    if (tid < N) {
        float m = -1e30f;
        for (int c = 0; c < CA; ++c) m = fmaxf(m, assS[tid*CA+c]);
        float s = 0.f;
        for (int c = 0; c < CA; ++c) s += expf(assS[tid*CA+c] - m);
        float m2 = -1e30f;
        for (int c = 0; c < CA; ++c) {
            float v = expf(assS[tid*CA+c] - m) / s;
            assS[tid*CA+c] = v;
            m2 = fmaxf(m2, v);
        }
        float s2sum = 0.f;
        for (int c = 0; c < CA; ++c) s2sum += expf(assS[tid*CA+c] - m2);
        for (int c = 0; c < CA; ++c) s2S[tid*CA+c] = expf(assS[tid*CA+c] - m2) / s2sum;
    }
    __syncthreads();
    // P22: Hc = s2^T @ H2g
    for (int o = tid; o < CA*20; o += NT) {
        int q = o/20, c = o%20;
        float acc = 0.f;
        for (int i = 0; i < N; ++i) acc += s2S[i*CA+q] * H2g[i*20+c];
        HcS[o] = acc;
    }
    __syncthreads();
    // P23: out = pooled + inter @ Hc
    for (int o = tid; o < KP*20; o += NT) {
        int k = o/20, c = o%20;
        int ip = permS[k];
        float v = H2g[ip*20+c] * scoreS[ip];
        int isp = spS[k];
        if (isp < 110) {
            float acc = 0.f;
            #pragma unroll 8
            for (int q = 0; q < CA; ++q) acc += assS[isp*CA+q] * HcS[q*20+c];
            v += acc;
        }
        out[(size_t)b*(KP*20) + o] = v;
    }
}

extern "C" void kernel_launch(void* const* d_in, const int* in_sizes, int n_in,
                              void* d_out, int out_size, void* d_ws, size_t ws_size,
                              hipStream_t stream) {
    const float* features   = (const float*)d_in[0];
    const float* edge_attr  = (const float*)d_in[1];
    // d_in[2] = adj (unused by reference)
    const int*   edge_index = (const int*)d_in[3];
    const float* Wl1 = (const float*)d_in[4];
    const float* bl1 = (const float*)d_in[5];
    const float* Wr1 = (const float*)d_in[6];
    const float* br1 = (const float*)d_in[7];
    const float* Wl2 = (const float*)d_in[8];
    const float* bl2 = (const float*)d_in[9];
    const float* Wr2 = (const float*)d_in[10];
    const float* br2 = (const float*)d_in[11];
    const float* Wg1 = (const float*)d_in[12];
    const float* bg1 = (const float*)d_in[13];
    const float* Wrel = (const float*)d_in[14];
    const float* brel = (const float*)d_in[15];
    const float* Wroot = (const float*)d_in[16];
    const float* Wc0 = (const float*)d_in[17];
    const float* Wc1 = (const float*)d_in[18];
    const float* Wc2 = (const float*)d_in[19];
    const float* bc  = (const float*)d_in[20];
    float* out = (float*)d_out;

    int B = in_sizes[0] / (N*N);
    brain_fused<<<dim3(B), dim3(NT), 0, stream>>>(
        features, edge_attr, edge_index,
        Wl1, bl1, Wr1, br1, Wl2, bl2, Wr2, br2, Wg1, bg1,
        Wrel, brel, Wroot, Wc0, Wc1, Wc2, bc, out);
}